// Round 11
// baseline (130.935 us; speedup 1.0000x reference)
//
#include <hip/hip_runtime.h>
#include <hip/hip_bf16.h>

#define NFEAT 128

typedef __bf16 bf16x8 __attribute__((ext_vector_type(8)));
typedef __bf16 bf16x4 __attribute__((ext_vector_type(4)));
typedef float f32x4 __attribute__((ext_vector_type(4)));
typedef float f32x2v __attribute__((ext_vector_type(2)));

// decode 8 packed fp8 e4m3 (OCP on gfx950) -> 4 packed float2
static __device__ __forceinline__ void fp8x8_to_2x4(uint2 p, f32x2v o[4]) {
    o[0] = __builtin_amdgcn_cvt_pk_f32_fp8(p.x, false);
    o[1] = __builtin_amdgcn_cvt_pk_f32_fp8(p.x, true);
    o[2] = __builtin_amdgcn_cvt_pk_f32_fp8(p.y, false);
    o[3] = __builtin_amdgcn_cvt_pk_f32_fp8(p.y, true);
}

// ---------------------------------------------------------------------------
// Dispatch 1 (prep, 128 blocks): swizzle+split W (fp32 [256,128]) into bf16
// MFMA layout for the fused x @ [W1|W2] GEMM (K=128, 256 cols):
//   wsw[((k>>3)*256 + n)*8 + (k&7)] = bf16( n<128 ? W[k][n] : W[128+k][n-128] )
// ---------------------------------------------------------------------------
__global__ __launch_bounds__(256) void prep(const float* __restrict__ w,
                                            __bf16* __restrict__ wsw) {
    int idx = blockIdx.x * 256 + threadIdx.x;  // 0..32767
    int k = idx >> 8, n = idx & 255;
    int row = (n < 128) ? k : 128 + k;
    wsw[(((k >> 3) * 256 + n) << 3) + (k & 7)] = (__bf16)w[row * 128 + (n & 127)];
}

// ---------------------------------------------------------------------------
// Dispatch 2: blocks [0,GB) GEMM z1 = bf16(x@W1 + bias), z2 = fp8(x@W2);
// blocks [GB,GB+EB) build CSR rowptr (consumed only by dispatch 3).
// TRANSPOSED MFMA: acc = mfma(Wfrag, xfrag, acc) so that D col(lane&15) =
// node row and D row(quad*4+r) = feature -> each lane's 4 regs per col-tile
// are 4 CONTIGUOUS features of one node: one 8B bf16x4 store (z1) or one
// packed 4B fp8x4 store (z2) per tile, vs 16 scattered 2B/1B stores before.
// GB = ntiles: one 16-row tile per block (max TLP, no loop).
// ---------------------------------------------------------------------------
__global__ __launch_bounds__(256, 2) void gemm_z(
    const float* __restrict__ x,      // [N,128] fp32
    const __bf16* __restrict__ wsw,   // swizzled [128,256] bf16
    const float* __restrict__ bias,   // [128] fp32
    const int* __restrict__ edst,     // [E] sorted
    int* __restrict__ rowptr,         // [N+1] out
    __bf16* __restrict__ z1,          // [N,128] bf16 out (bias folded)
    unsigned char* __restrict__ z2,   // [N,128] fp8 out
    int N, int E, int GB) {
    if ((int)blockIdx.x >= GB) {
        int e = ((int)blockIdx.x - GB) * 256 + threadIdx.x;
        if (e >= E) return;
        int d = edst[e];
        int prev = (e == 0) ? -1 : edst[e - 1];
        for (int v = prev + 1; v <= d; ++v) rowptr[v] = e;
        if (e == E - 1)
            for (int v = d + 1; v <= N; ++v) rowptr[v] = E;
        return;
    }

    int t = threadIdx.x;
    int q = t >> 6;          // wave = 64-col quarter of [W1|W2]
    int lane = t & 63;
    int m = lane & 15;       // node row within tile (D col) & W-frag lane idx
    int quad = lane >> 4;
    int colbase = q * 64 + m;
    int tile = blockIdx.x;

    // W fragments (A-operand of the transposed product): lane m holds
    // Wh[k = ks*32+quad*8+j][n = q*64 + ct*16 + m] -- same 16B reads as before
    bf16x8 Wf[4][4];
#pragma unroll
    for (int ks = 0; ks < 4; ++ks)
#pragma unroll
        for (int ct = 0; ct < 4; ++ct)
            Wf[ks][ct] = *(const bf16x8*)(wsw +
                (((size_t)(ks * 4 + quad) * 256 + colbase + ct * 16) << 3));

    // bias for the 4 contiguous features this lane owns per col-tile
    f32x4 bi[4];
#pragma unroll
    for (int ct = 0; ct < 4; ++ct)
        bi[ct] = (q < 2) ? *(const f32x4*)(bias + q * 64 + ct * 16 + quad * 4)
                         : (f32x4)(0.f);

    // x fragments (B-operand): lane m holds x[row = tile*16+m][k-slice]
    int row = tile * 16 + m;
    int rowc = min(row, N - 1);
    bf16x8 Xf[4];
#pragma unroll
    for (int ks = 0; ks < 4; ++ks) {
        const float* ap = x + (size_t)rowc * 128 + ks * 32 + quad * 8;
        f32x4 lo = *(const f32x4*)ap;
        f32x4 hi = *(const f32x4*)(ap + 4);
        bf16x8 af;
#pragma unroll
        for (int j = 0; j < 4; ++j) {
            af[j] = (__bf16)lo[j];
            af[j + 4] = (__bf16)hi[j];
        }
        Xf[ks] = af;
    }

    f32x4 acc[4];
#pragma unroll
    for (int ct = 0; ct < 4; ++ct) acc[ct] = (f32x4)(0.f);
#pragma unroll
    for (int ks = 0; ks < 4; ++ks)
#pragma unroll
        for (int ct = 0; ct < 4; ++ct)
            acc[ct] = __builtin_amdgcn_mfma_f32_16x16x32_bf16(
                Wf[ks][ct], Xf[ks], acc[ct], 0, 0, 0);

    // epilogue: D col = lane&15 = node row (single bounds check),
    //           D row = quad*4+r = feature within the ct-th 16-col tile.
    int rr = tile * 16 + m;
    if (rr >= N) return;
    if (q < 2) {
#pragma unroll
        for (int ct = 0; ct < 4; ++ct) {
            int f0 = q * 64 + ct * 16 + quad * 4;
            bf16x4 v;
#pragma unroll
            for (int r = 0; r < 4; ++r)
                v[r] = (__bf16)(acc[ct][r] + bi[ct][r]);
            *(bf16x4*)(z1 + (size_t)rr * 128 + f0) = v;  // one 8B store
        }
    } else {
#pragma unroll
        for (int ct = 0; ct < 4; ++ct) {
            int f0 = (q - 2) * 64 + ct * 16 + quad * 4;
            int lo = __builtin_amdgcn_cvt_pk_fp8_f32(acc[ct][0], acc[ct][1],
                                                     0, false);
            int full = __builtin_amdgcn_cvt_pk_fp8_f32(acc[ct][2], acc[ct][3],
                                                       lo, true);
            *(unsigned int*)(z2 + (size_t)rr * 128 + f0) =
                (unsigned int)full;                      // one 4B store
        }
    }
}

// ---------------------------------------------------------------------------
// Dispatch 3: out[v] = relu( z1[v] + sum_e w_e * z2[src_e] ), fp32.
// One wave per node (12500-block grid: TLP hides gather latency; r9 showed
// persistent grids destroy this). Edge metadata loaded once coalesced,
// broadcast via __shfl; 16 edges/iter = 4 independent 8B gathers per
// feature-group; packed v_pk_fma_f32 accumulate.
// ---------------------------------------------------------------------------
__global__ __launch_bounds__(256) void agg_out(
    const __bf16* __restrict__ z1,          // [N,128] bf16 (bias folded)
    const unsigned char* __restrict__ z2,   // [N,128] fp8
    const int* __restrict__ esrc,           // [E]
    const float* __restrict__ ew,           // [E] fp32
    const int* __restrict__ rowptr,         // [N+1]
    float* __restrict__ out,                // [N,128] fp32
    int N) {
    int wave = threadIdx.x >> 6;
    int lane = threadIdx.x & 63;
    int v = blockIdx.x * 4 + wave;
    if (v >= N) return;
    int g = lane >> 4;
    int c = lane & 15;

    // self term first: independent load, overlaps the whole gather chain
    bf16x8 s1 = *(const bf16x8*)(z1 + (size_t)v * 128 + (c << 3));

    int e0 = rowptr[v], e1 = rowptr[v + 1];
    int deg = e1 - e0;

    // coalesced per-node metadata: lane l holds edge e0+l
    int me = e0 + lane;
    int s_l = 0;
    float w_l = 0.f;
    if (me < e1) {
        s_l = esrc[me];
        w_l = ew[me];
    }

    f32x2v acc2[4];
#pragma unroll
    for (int j = 0; j < 4; ++j) acc2[j] = (f32x2v)(0.f);

    const unsigned char* gbase = z2 + (c << 3);
    int dmax = (deg < 64) ? deg : 64;
    for (int base = 0; base < dmax; base += 16) {
        int ss[4];
        float ww[4];
        uint2 p[4];
#pragma unroll
        for (int u = 0; u < 4; ++u) {
            int idx = base + u * 4 + g;
            ss[u] = __shfl(s_l, idx);
            ww[u] = __shfl(w_l, idx);  // 0 beyond deg
            p[u] = *(const uint2*)(gbase + (size_t)ss[u] * 128);
        }
#pragma unroll
        for (int u = 0; u < 4; ++u) {
            f32x2v d[4];
            fp8x8_to_2x4(p[u], d);
            f32x2v w2 = {ww[u], ww[u]};
#pragma unroll
            for (int j = 0; j < 4; ++j) acc2[j] += w2 * d[j];  // v_pk_fma_f32
        }
    }
    for (int bb = e0 + 64; bb < e1; bb += 4) {  // deg>64 fallback (rare)
        int ee = bb + g;
        int eec = min(ee, e1 - 1);
        int ss = esrc[eec];
        float ww = (ee < e1) ? ew[eec] : 0.f;
        uint2 p = *(const uint2*)(gbase + (size_t)ss * 128);
        f32x2v d[4];
        fp8x8_to_2x4(p, d);
        f32x2v w2 = {ww, ww};
#pragma unroll
        for (int j = 0; j < 4; ++j) acc2[j] += w2 * d[j];
    }

    float acc[8];
#pragma unroll
    for (int j = 0; j < 8; ++j) acc[j] = acc2[j >> 1][j & 1];

    // merge the 4 edge-groups (lane bits 4,5)
#pragma unroll
    for (int j = 0; j < 8; ++j) acc[j] += __shfl_xor(acc[j], 16, 64);
#pragma unroll
    for (int j = 0; j < 8; ++j) acc[j] += __shfl_xor(acc[j], 32, 64);

    float r[8];
#pragma unroll
    for (int j = 0; j < 8; ++j)
        r[j] = fmaxf((float)s1[j] + acc[j], 0.f);

    float* op = out + (size_t)v * 128 + (c << 3);
    if (g == 0) {
        f32x4 s = {r[0], r[1], r[2], r[3]};
        *(f32x4*)op = s;
    } else if (g == 1) {
        f32x4 s = {r[4], r[5], r[6], r[7]};
        *(f32x4*)(op + 4) = s;
    }
}

// ---------------------------------------------------------------------------
extern "C" void kernel_launch(void* const* d_in, const int* in_sizes, int n_in,
                              void* d_out, int out_size, void* d_ws,
                              size_t ws_size, hipStream_t stream) {
    const float* x = (const float*)d_in[0];
    const int* esrc = (const int*)d_in[1];
    const int* edst = (const int*)d_in[2];
    const float* ew = (const float*)d_in[3];
    const float* w = (const float*)d_in[4];
    const float* bias = (const float*)d_in[5];
    float* out = (float*)d_out;

    int N = in_sizes[0] / NFEAT;
    int E = in_sizes[1];

    // workspace layout
    char* ws = (char*)d_ws;
    __bf16* z1 = (__bf16*)ws;                             // 12.8 MB
    size_t z1_bytes = ((size_t)N * 128 * 2 + 255) & ~(size_t)255;
    unsigned char* z2 = (unsigned char*)(ws + z1_bytes);  // 6.4 MB
    size_t z2_bytes = ((size_t)N * 128 + 255) & ~(size_t)255;
    __bf16* wsw = (__bf16*)(ws + z1_bytes + z2_bytes);    // 64 KB
    int* rowptr = (int*)(ws + z1_bytes + z2_bytes + 65536);

    int ntiles = (N + 15) / 16;     // one 16-row tile per block
    int EB = (E + 255) / 256;
    prep<<<128, 256, 0, stream>>>(w, wsw);
    gemm_z<<<ntiles + EB, 256, 0, stream>>>(x, wsw, bias, edst, rowptr, z1, z2,
                                            N, E, ntiles);
    agg_out<<<(N + 3) / 4, 256, 0, stream>>>(z1, z2, esrc, ew, rowptr, out, N);
}

// Round 12
// 122.807 us; speedup vs baseline: 1.0662x; 1.0662x over previous
//
#include <hip/hip_runtime.h>
#include <hip/hip_bf16.h>

#define NFEAT 128

typedef __bf16 bf16x8 __attribute__((ext_vector_type(8)));
typedef float f32x4 __attribute__((ext_vector_type(4)));
typedef float f32x2v __attribute__((ext_vector_type(2)));

// decode 8 packed fp8 e4m3 (OCP on gfx950) -> 4 packed float2
static __device__ __forceinline__ void fp8x8_to_2x4(uint2 p, f32x2v o[4]) {
    o[0] = __builtin_amdgcn_cvt_pk_f32_fp8(p.x, false);
    o[1] = __builtin_amdgcn_cvt_pk_f32_fp8(p.x, true);
    o[2] = __builtin_amdgcn_cvt_pk_f32_fp8(p.y, false);
    o[3] = __builtin_amdgcn_cvt_pk_f32_fp8(p.y, true);
}

// encode one float -> fp8 e4m3 byte (RNE; |v| << 448 here so no saturation)
static __device__ __forceinline__ unsigned char f32_to_fp8(float v) {
    int r = __builtin_amdgcn_cvt_pk_fp8_f32(v, v, 0, false);
    return (unsigned char)(r & 0xff);
}

// ---------------------------------------------------------------------------
// Dispatch 1 (prep, 128 blocks): swizzle+split W (fp32 [256,128]) into bf16
// MFMA-B layout for the fused x @ [W1|W2] GEMM (K=128, 256 cols):
//   wsw[((k>>3)*256 + n)*8 + (k&7)] = bf16( n<128 ? W[k][n] : W[128+k][n-128] )
// ---------------------------------------------------------------------------
__global__ __launch_bounds__(256) void prep(const float* __restrict__ w,
                                            __bf16* __restrict__ wsw) {
    int idx = blockIdx.x * 256 + threadIdx.x;  // 0..32767
    int k = idx >> 8, n = idx & 255;
    int row = (n < 128) ? k : 128 + k;
    wsw[(((k >> 3) * 256 + n) << 3) + (k & 7)] = (__bf16)w[row * 128 + (n & 127)];
}

// ---------------------------------------------------------------------------
// Dispatch 2: blocks [0,GB) GEMM z1 = bf16(x@W1 + bias), z2 = fp8(x@W2);
// blocks [GB,GB+EB) build CSR rowptr (consumed only by dispatch 3).
// Register-resident B from swizzled wsw (16 coalesced 16B reads per wave,
// amortized over ~3 tiles at GB=1024). Wave q = 64-col quarter of [W1|W2];
// 4 waves cover one 16-row tile. Stores are lane-coalesced (consecutive m
// -> consecutive addresses) -- r11 showed per-lane payload matters less
// than lane-contiguity.
// ---------------------------------------------------------------------------
__global__ __launch_bounds__(256, 2) void gemm_z(
    const float* __restrict__ x,      // [N,128] fp32
    const __bf16* __restrict__ wsw,   // swizzled [128,256] bf16
    const float* __restrict__ bias,   // [128] fp32
    const int* __restrict__ edst,     // [E] sorted
    int* __restrict__ rowptr,         // [N+1] out
    __bf16* __restrict__ z1,          // [N,128] bf16 out (bias folded)
    unsigned char* __restrict__ z2,   // [N,128] fp8 out
    int N, int E, int ntiles, int GB) {
    if ((int)blockIdx.x >= GB) {
        int e = ((int)blockIdx.x - GB) * 256 + threadIdx.x;
        if (e >= E) return;
        int d = edst[e];
        int prev = (e == 0) ? -1 : edst[e - 1];
        for (int v = prev + 1; v <= d; ++v) rowptr[v] = e;
        if (e == E - 1)
            for (int v = d + 1; v <= N; ++v) rowptr[v] = E;
        return;
    }

    int t = threadIdx.x;
    int q = t >> 6;          // wave = column quarter of [W1|W2]
    int lane = t & 63;
    int m = lane & 15;
    int quad = lane >> 4;
    int colbase = q * 64 + m;

    bf16x8 B[4][4];  // 64 VGPRs, coalesced 16B reads
#pragma unroll
    for (int ks = 0; ks < 4; ++ks)
#pragma unroll
        for (int ct = 0; ct < 4; ++ct)
            B[ks][ct] = *(const bf16x8*)(wsw +
                (((size_t)(ks * 4 + quad) * 256 + colbase + ct * 16) << 3));

    float bi[4];
#pragma unroll
    for (int ct = 0; ct < 4; ++ct)
        bi[ct] = (q < 2) ? bias[colbase + ct * 16] : 0.f;

    for (int tile = blockIdx.x; tile < ntiles; tile += GB) {
        int row = tile * 16 + m;
        int rowc = min(row, N - 1);
        bf16x8 A[4];
#pragma unroll
        for (int ks = 0; ks < 4; ++ks) {
            const float* ap = x + (size_t)rowc * 128 + ks * 32 + quad * 8;
            f32x4 lo = *(const f32x4*)ap;
            f32x4 hi = *(const f32x4*)(ap + 4);
            bf16x8 af;
#pragma unroll
            for (int j = 0; j < 4; ++j) {
                af[j] = (__bf16)lo[j];
                af[j + 4] = (__bf16)hi[j];
            }
            A[ks] = af;
        }

        f32x4 acc[4];
#pragma unroll
        for (int ct = 0; ct < 4; ++ct) acc[ct] = (f32x4)(0.f);
#pragma unroll
        for (int ks = 0; ks < 4; ++ks)
#pragma unroll
            for (int ct = 0; ct < 4; ++ct)
                acc[ct] = __builtin_amdgcn_mfma_f32_16x16x32_bf16(
                    A[ks], B[ks][ct], acc[ct], 0, 0, 0);

        int orow = tile * 16 + quad * 4;  // D: col=lane&15, row=quad*4+r
        if (q < 2) {
#pragma unroll
            for (int ct = 0; ct < 4; ++ct) {
                int col = colbase + ct * 16;
#pragma unroll
                for (int r = 0; r < 4; ++r) {
                    int rr = orow + r;
                    if (rr < N)
                        z1[(size_t)rr * 128 + col] =
                            (__bf16)(acc[ct][r] + bi[ct]);
                }
            }
        } else {
#pragma unroll
            for (int ct = 0; ct < 4; ++ct) {
                int col = colbase + ct * 16 - 128;
#pragma unroll
                for (int r = 0; r < 4; ++r) {
                    int rr = orow + r;
                    if (rr < N)
                        z2[(size_t)rr * 128 + col] = f32_to_fp8(acc[ct][r]);
                }
            }
        }
    }
}

// ---------------------------------------------------------------------------
// Dispatch 3: out[v] = relu( z1[v] + sum_e w_e * z2[src_e] ), fp32.
// TWO nodes per wave (32 lanes each: h=lane>>5 node select). Per half:
// g=bit4 edge subgroup, c=lane&15 feature chunk (8B of the 128B row).
// Metadata (deg<=32) loaded once coalesced per half, broadcast via __shfl;
// 8 edges/node/iter -> 8 independent gathers in flight per wave (2x r10's
// MLP); single-stage butterfly (xor 16); all 64 lanes store the output.
// Fat grid (6250 blocks): r9 showed TLP >> persistent-grid fusion.
// ---------------------------------------------------------------------------
__global__ __launch_bounds__(256) void agg_out(
    const __bf16* __restrict__ z1,          // [N,128] bf16 (bias folded)
    const unsigned char* __restrict__ z2,   // [N,128] fp8
    const int* __restrict__ esrc,           // [E]
    const float* __restrict__ ew,           // [E] fp32
    const int* __restrict__ rowptr,         // [N+1]
    float* __restrict__ out,                // [N,128] fp32
    int N) {
    int wave = threadIdx.x >> 6;
    int lane = threadIdx.x & 63;
    int h = lane >> 5;        // node select within wave
    int lane32 = lane & 31;
    int g = lane32 >> 4;      // edge subgroup (2 per node)
    int c = lane32 & 15;      // feature chunk

    int v = blockIdx.x * 8 + wave * 2 + h;
    bool valid = v < N;
    int vc = valid ? v : N - 1;

    int e0 = rowptr[vc], e1 = rowptr[vc + 1];
    if (!valid) e1 = e0;      // dead half: no edges, no store
    int deg = e1 - e0;

    // self term: independent load, overlaps the gather chain
    bf16x8 s1 = *(const bf16x8*)(z1 + (size_t)vc * 128 + (c << 3));

    // coalesced per-half metadata: lane32 l holds edge e0+l (deg<=32 path)
    int me = e0 + lane32;
    int s_l = 0;
    float w_l = 0.f;
    if (me < e1) {
        s_l = esrc[me];
        w_l = ew[me];
    }

    f32x2v acc2[4];
#pragma unroll
    for (int j = 0; j < 4; ++j) acc2[j] = (f32x2v)(0.f);

    const unsigned char* gbase = z2 + (c << 3);
    int dmax = (deg < 32) ? deg : 32;
    for (int base = 0; base < dmax; base += 8) {
        int ss[4];
        float ww[4];
        uint2 p[4];
#pragma unroll
        for (int u = 0; u < 4; ++u) {
            int src = (h << 5) + base + u * 2 + g;  // stays within this half
            ss[u] = __shfl(s_l, src, 64);
            ww[u] = __shfl(w_l, src, 64);           // 0 beyond deg
            p[u] = *(const uint2*)(gbase + (size_t)ss[u] * 128);
        }
#pragma unroll
        for (int u = 0; u < 4; ++u) {
            f32x2v d[4];
            fp8x8_to_2x4(p[u], d);
            f32x2v w2 = {ww[u], ww[u]};
#pragma unroll
            for (int j = 0; j < 4; ++j) acc2[j] += w2 * d[j];  // v_pk_fma_f32
        }
    }
    for (int bb = e0 + 32; bb < e1; bb += 2) {  // deg>32 fallback (~2e-4)
        int ee = bb + g;
        int eec = min(ee, e1 - 1);
        int ssf = esrc[eec];
        float wwf = (ee < e1) ? ew[eec] : 0.f;
        uint2 p = *(const uint2*)(gbase + (size_t)ssf * 128);
        f32x2v d[4];
        fp8x8_to_2x4(p, d);
        f32x2v w2 = {wwf, wwf};
#pragma unroll
        for (int j = 0; j < 4; ++j) acc2[j] += w2 * d[j];
    }

    float acc[8];
#pragma unroll
    for (int j = 0; j < 8; ++j) acc[j] = acc2[j >> 1][j & 1];

    // merge the 2 edge-groups within each 32-lane half (lane bit 4)
#pragma unroll
    for (int j = 0; j < 8; ++j) acc[j] += __shfl_xor(acc[j], 16, 64);

    float r[8];
#pragma unroll
    for (int j = 0; j < 8; ++j)
        r[j] = fmaxf((float)s1[j] + acc[j], 0.f);

    if (valid) {
        float* op = out + (size_t)v * 128 + (c << 3);
        if (g == 0) {
            f32x4 s = {r[0], r[1], r[2], r[3]};
            *(f32x4*)op = s;
        } else {
            f32x4 s = {r[4], r[5], r[6], r[7]};
            *(f32x4*)(op + 4) = s;
        }
    }
}

// ---------------------------------------------------------------------------
extern "C" void kernel_launch(void* const* d_in, const int* in_sizes, int n_in,
                              void* d_out, int out_size, void* d_ws,
                              size_t ws_size, hipStream_t stream) {
    const float* x = (const float*)d_in[0];
    const int* esrc = (const int*)d_in[1];
    const int* edst = (const int*)d_in[2];
    const float* ew = (const float*)d_in[3];
    const float* w = (const float*)d_in[4];
    const float* bias = (const float*)d_in[5];
    float* out = (float*)d_out;

    int N = in_sizes[0] / NFEAT;
    int E = in_sizes[1];

    // workspace layout
    char* ws = (char*)d_ws;
    __bf16* z1 = (__bf16*)ws;                             // 12.8 MB
    size_t z1_bytes = ((size_t)N * 128 * 2 + 255) & ~(size_t)255;
    unsigned char* z2 = (unsigned char*)(ws + z1_bytes);  // 6.4 MB
    size_t z2_bytes = ((size_t)N * 128 + 255) & ~(size_t)255;
    __bf16* wsw = (__bf16*)(ws + z1_bytes + z2_bytes);    // 64 KB
    int* rowptr = (int*)(ws + z1_bytes + z2_bytes + 65536);

    int ntiles = (N + 15) / 16;
    int GB = 1024;
    int EB = (E + 255) / 256;
    prep<<<128, 256, 0, stream>>>(w, wsw);
    gemm_z<<<GB + EB, 256, 0, stream>>>(x, wsw, bias, edst, rowptr, z1, z2, N,
                                        E, ntiles, GB);
    agg_out<<<(N + 7) / 8, 256, 0, stream>>>(z1, z2, esrc, ew, rowptr, out, N);
}

// Round 13
// 121.577 us; speedup vs baseline: 1.0770x; 1.0101x over previous
//
#include <hip/hip_runtime.h>
#include <hip/hip_bf16.h>

#define NFEAT 128

typedef __bf16 bf16x8 __attribute__((ext_vector_type(8)));
typedef float f32x4 __attribute__((ext_vector_type(4)));
typedef float f32x2v __attribute__((ext_vector_type(2)));

// decode 8 packed fp8 e4m3 (OCP on gfx950) -> 4 packed float2
static __device__ __forceinline__ void fp8x8_to_2x4(uint2 p, f32x2v o[4]) {
    o[0] = __builtin_amdgcn_cvt_pk_f32_fp8(p.x, false);
    o[1] = __builtin_amdgcn_cvt_pk_f32_fp8(p.x, true);
    o[2] = __builtin_amdgcn_cvt_pk_f32_fp8(p.y, false);
    o[3] = __builtin_amdgcn_cvt_pk_f32_fp8(p.y, true);
}

// encode one float -> fp8 e4m3 byte (RNE; |v| << 448 here so no saturation)
static __device__ __forceinline__ unsigned char f32_to_fp8(float v) {
    int r = __builtin_amdgcn_cvt_pk_fp8_f32(v, v, 0, false);
    return (unsigned char)(r & 0xff);
}

// ---------------------------------------------------------------------------
// Dispatch 1 (prep, 128 blocks): swizzle+split W (fp32 [256,128]) into bf16
// MFMA-B layout for the fused x @ [W1|W2] GEMM (K=128, 256 cols):
//   wsw[((k>>3)*256 + n)*8 + (k&7)] = bf16( n<128 ? W[k][n] : W[128+k][n-128] )
// ---------------------------------------------------------------------------
__global__ __launch_bounds__(256) void prep(const float* __restrict__ w,
                                            __bf16* __restrict__ wsw) {
    int idx = blockIdx.x * 256 + threadIdx.x;  // 0..32767
    int k = idx >> 8, n = idx & 255;
    int row = (n < 128) ? k : 128 + k;
    wsw[(((k >> 3) * 256 + n) << 3) + (k & 7)] = (__bf16)w[row * 128 + (n & 127)];
}

// ---------------------------------------------------------------------------
// Dispatch 2: blocks [0,GB) GEMM z1 = bf16(x@W1 + bias), z2 = fp8(x@W2);
// blocks [GB,GB+EB) build CSR rowptr (consumed only by dispatch 3).
// Register-resident B from swizzled wsw (16 coalesced 16B reads per wave,
// amortized over ~3 tiles at GB=1024). Wave q = 64-col quarter of [W1|W2];
// 4 waves cover one 16-row tile. Stores are lane-coalesced (consecutive m
// -> consecutive addresses) -- r11 showed lane-contiguity beats per-lane
// payload.
// ---------------------------------------------------------------------------
__global__ __launch_bounds__(256, 2) void gemm_z(
    const float* __restrict__ x,      // [N,128] fp32
    const __bf16* __restrict__ wsw,   // swizzled [128,256] bf16
    const float* __restrict__ bias,   // [128] fp32
    const int* __restrict__ edst,     // [E] sorted
    int* __restrict__ rowptr,         // [N+1] out
    __bf16* __restrict__ z1,          // [N,128] bf16 out (bias folded)
    unsigned char* __restrict__ z2,   // [N,128] fp8 out
    int N, int E, int ntiles, int GB) {
    if ((int)blockIdx.x >= GB) {
        int e = ((int)blockIdx.x - GB) * 256 + threadIdx.x;
        if (e >= E) return;
        int d = edst[e];
        int prev = (e == 0) ? -1 : edst[e - 1];
        for (int v = prev + 1; v <= d; ++v) rowptr[v] = e;
        if (e == E - 1)
            for (int v = d + 1; v <= N; ++v) rowptr[v] = E;
        return;
    }

    int t = threadIdx.x;
    int q = t >> 6;          // wave = column quarter of [W1|W2]
    int lane = t & 63;
    int m = lane & 15;
    int quad = lane >> 4;
    int colbase = q * 64 + m;

    bf16x8 B[4][4];  // 64 VGPRs, coalesced 16B reads
#pragma unroll
    for (int ks = 0; ks < 4; ++ks)
#pragma unroll
        for (int ct = 0; ct < 4; ++ct)
            B[ks][ct] = *(const bf16x8*)(wsw +
                (((size_t)(ks * 4 + quad) * 256 + colbase + ct * 16) << 3));

    float bi[4];
#pragma unroll
    for (int ct = 0; ct < 4; ++ct)
        bi[ct] = (q < 2) ? bias[colbase + ct * 16] : 0.f;

    for (int tile = blockIdx.x; tile < ntiles; tile += GB) {
        int row = tile * 16 + m;
        int rowc = min(row, N - 1);
        bf16x8 A[4];
#pragma unroll
        for (int ks = 0; ks < 4; ++ks) {
            const float* ap = x + (size_t)rowc * 128 + ks * 32 + quad * 8;
            f32x4 lo = *(const f32x4*)ap;
            f32x4 hi = *(const f32x4*)(ap + 4);
            bf16x8 af;
#pragma unroll
            for (int j = 0; j < 4; ++j) {
                af[j] = (__bf16)lo[j];
                af[j + 4] = (__bf16)hi[j];
            }
            A[ks] = af;
        }

        f32x4 acc[4];
#pragma unroll
        for (int ct = 0; ct < 4; ++ct) acc[ct] = (f32x4)(0.f);
#pragma unroll
        for (int ks = 0; ks < 4; ++ks)
#pragma unroll
            for (int ct = 0; ct < 4; ++ct)
                acc[ct] = __builtin_amdgcn_mfma_f32_16x16x32_bf16(
                    A[ks], B[ks][ct], acc[ct], 0, 0, 0);

        int orow = tile * 16 + quad * 4;  // D: col=lane&15, row=quad*4+r
        if (q < 2) {
#pragma unroll
            for (int ct = 0; ct < 4; ++ct) {
                int col = colbase + ct * 16;
#pragma unroll
                for (int r = 0; r < 4; ++r) {
                    int rr = orow + r;
                    if (rr < N)
                        z1[(size_t)rr * 128 + col] =
                            (__bf16)(acc[ct][r] + bi[ct]);
                }
            }
        } else {
#pragma unroll
            for (int ct = 0; ct < 4; ++ct) {
                int col = colbase + ct * 16 - 128;
#pragma unroll
                for (int r = 0; r < 4; ++r) {
                    int rr = orow + r;
                    if (rr < N)
                        z2[(size_t)rr * 128 + col] = f32_to_fp8(acc[ct][r]);
                }
            }
        }
    }
}

// ---------------------------------------------------------------------------
// Dispatch 3: out[v] = relu( z1[v] + sum_e w_e * z2[src_e] ), fp32.
// TWO nodes per wave (32 lanes each: h=lane>>5). Per half: g=bit4 edge
// subgroup, c=lane&15 feature chunk. Metadata (deg<=32) loaded once
// coalesced per half, broadcast via __shfl. WIDE inner iteration: 16 edges
// per node per iter -> 8 independent gather instructions in flight (32
// edge-rows across the wave's 4 subgroups); deg<=16 (median) completes the
// gather phase in ONE iteration. Single-stage butterfly; all lanes store.
// ---------------------------------------------------------------------------
__global__ __launch_bounds__(256) void agg_out(
    const __bf16* __restrict__ z1,          // [N,128] bf16 (bias folded)
    const unsigned char* __restrict__ z2,   // [N,128] fp8
    const int* __restrict__ esrc,           // [E]
    const float* __restrict__ ew,           // [E] fp32
    const int* __restrict__ rowptr,         // [N+1]
    float* __restrict__ out,                // [N,128] fp32
    int N) {
    int wave = threadIdx.x >> 6;
    int lane = threadIdx.x & 63;
    int h = lane >> 5;        // node select within wave
    int lane32 = lane & 31;
    int g = lane32 >> 4;      // edge subgroup (2 per node)
    int c = lane32 & 15;      // feature chunk

    int v = blockIdx.x * 8 + wave * 2 + h;
    bool valid = v < N;
    int vc = valid ? v : N - 1;

    int e0 = rowptr[vc], e1 = rowptr[vc + 1];
    if (!valid) e1 = e0;      // dead half: no edges, no store
    int deg = e1 - e0;

    // self term: independent load, overlaps the gather chain
    bf16x8 s1 = *(const bf16x8*)(z1 + (size_t)vc * 128 + (c << 3));

    // coalesced per-half metadata: lane32 l holds edge e0+l (deg<=32 path)
    int me = e0 + lane32;
    int s_l = 0;
    float w_l = 0.f;
    if (me < e1) {
        s_l = esrc[me];
        w_l = ew[me];
    }

    f32x2v acc2[4];
#pragma unroll
    for (int j = 0; j < 4; ++j) acc2[j] = (f32x2v)(0.f);

    const unsigned char* gbase = z2 + (c << 3);
    int dmax = (deg < 32) ? deg : 32;
    for (int base = 0; base < dmax; base += 16) {
        int ss[8];
        float ww[8];
        uint2 p[8];
#pragma unroll
        for (int u = 0; u < 8; ++u) {
            int src = (h << 5) + base + u * 2 + g;  // stays within this half
            ss[u] = __shfl(s_l, src, 64);
            ww[u] = __shfl(w_l, src, 64);           // 0 beyond deg
            p[u] = *(const uint2*)(gbase + (size_t)ss[u] * 128);
        }
#pragma unroll
        for (int u = 0; u < 8; ++u) {
            f32x2v d[4];
            fp8x8_to_2x4(p[u], d);
            f32x2v w2 = {ww[u], ww[u]};
#pragma unroll
            for (int j = 0; j < 4; ++j) acc2[j] += w2 * d[j];  // v_pk_fma_f32
        }
    }
    for (int bb = e0 + 32; bb < e1; bb += 2) {  // deg>32 fallback (~2e-4)
        int ee = bb + g;
        int eec = min(ee, e1 - 1);
        int ssf = esrc[eec];
        float wwf = (ee < e1) ? ew[eec] : 0.f;
        uint2 p = *(const uint2*)(gbase + (size_t)ssf * 128);
        f32x2v d[4];
        fp8x8_to_2x4(p, d);
        f32x2v w2 = {wwf, wwf};
#pragma unroll
        for (int j = 0; j < 4; ++j) acc2[j] += w2 * d[j];
    }

    float acc[8];
#pragma unroll
    for (int j = 0; j < 8; ++j) acc[j] = acc2[j >> 1][j & 1];

    // merge the 2 edge-groups within each 32-lane half (lane bit 4)
#pragma unroll
    for (int j = 0; j < 8; ++j) acc[j] += __shfl_xor(acc[j], 16, 64);

    float r[8];
#pragma unroll
    for (int j = 0; j < 8; ++j)
        r[j] = fmaxf((float)s1[j] + acc[j], 0.f);

    if (valid) {
        float* op = out + (size_t)v * 128 + (c << 3);
        if (g == 0) {
            f32x4 s = {r[0], r[1], r[2], r[3]};
            *(f32x4*)op = s;
        } else {
            f32x4 s = {r[4], r[5], r[6], r[7]};
            *(f32x4*)(op + 4) = s;
        }
    }
}

// ---------------------------------------------------------------------------
extern "C" void kernel_launch(void* const* d_in, const int* in_sizes, int n_in,
                              void* d_out, int out_size, void* d_ws,
                              size_t ws_size, hipStream_t stream) {
    const float* x = (const float*)d_in[0];
    const int* esrc = (const int*)d_in[1];
    const int* edst = (const int*)d_in[2];
    const float* ew = (const float*)d_in[3];
    const float* w = (const float*)d_in[4];
    const float* bias = (const float*)d_in[5];
    float* out = (float*)d_out;

    int N = in_sizes[0] / NFEAT;
    int E = in_sizes[1];

    // workspace layout
    char* ws = (char*)d_ws;
    __bf16* z1 = (__bf16*)ws;                             // 12.8 MB
    size_t z1_bytes = ((size_t)N * 128 * 2 + 255) & ~(size_t)255;
    unsigned char* z2 = (unsigned char*)(ws + z1_bytes);  // 6.4 MB
    size_t z2_bytes = ((size_t)N * 128 + 255) & ~(size_t)255;
    __bf16* wsw = (__bf16*)(ws + z1_bytes + z2_bytes);    // 64 KB
    int* rowptr = (int*)(ws + z1_bytes + z2_bytes + 65536);

    int ntiles = (N + 15) / 16;
    int GB = 1024;
    int EB = (E + 255) / 256;
    prep<<<128, 256, 0, stream>>>(w, wsw);
    gemm_z<<<GB + EB, 256, 0, stream>>>(x, wsw, bias, edst, rowptr, z1, z2, N,
                                        E, ntiles, GB);
    agg_out<<<(N + 7) / 8, 256, 0, stream>>>(z1, z2, esrc, ew, rowptr, out, N);
}